// Round 1
// baseline (10866.090 us; speedup 1.0000x reference)
//
#include <hip/hip_runtime.h>

// Decoder scan: B=1024, T=128, M=256, P=256, 127 steps.
// R3: XW score tile is step-invariant per wave (16 KB) -> hoist into 64 VGPRs
// (16 x uint4 per lane) before the scan loop. Eliminates the per-step 8 MB/XCD
// XW stream (L2 thrash + L3 latency) that dominated the 37 us/step stall.
// Weights W1F/W2F now stay L2-resident. Scores phase is pure VALU from regs.

#define B_SZ 1024
#define T_SZ 128
#define M_SZ 256
#define NSTEP 127

typedef __attribute__((ext_vector_type(8))) short short8;
typedef __attribute__((ext_vector_type(4))) float f32x4;

__device__ __forceinline__ float bf2f_lo(unsigned u) {
  return __builtin_bit_cast(float, u << 16);
}
__device__ __forceinline__ float bf2f_hi(unsigned u) {
  return __builtin_bit_cast(float, u & 0xffff0000u);
}
__device__ __forceinline__ unsigned short f2bf(float f) {
  unsigned u = __builtin_bit_cast(unsigned, f);
  u = (u + 0x7fffu + ((u >> 16) & 1u)) >> 16;  // RNE
  return (unsigned short)u;
}
__device__ __forceinline__ float fexp2(float x) { return __builtin_amdgcn_exp2f(x); }
__device__ __forceinline__ float frcp(float x) { return __builtin_amdgcn_rcpf(x); }
__device__ __forceinline__ float tanh_f(float x) {
  float t = fexp2(x * 2.8853900817779268f);
  return 1.f - 2.f * frcp(t + 1.f);
}
__device__ __forceinline__ float sigm_f(float x) {
  return frcp(1.f + fexp2(x * -1.4426950408889634f));
}
__device__ __forceinline__ short8 as_s8(uint4 u) { return __builtin_bit_cast(short8, u); }

// ---------------- prep: weight bf16 fragment swizzles + bias sum ----------------
__global__ void prep_w(const float* __restrict__ WU_d,
                       const float* __restrict__ W_hh,
                       const float* __restrict__ b_ih,
                       const float* __restrict__ b_hh,
                       unsigned short* __restrict__ W1F,
                       unsigned short* __restrict__ W2F,
                       unsigned short* __restrict__ WxF,
                       float* __restrict__ bsum) {
  int i = blockIdx.x * 256 + threadIdx.x;
  if (i < 131072) {
    int j = i & 7, lane = (i >> 3) & 63, ks = (i >> 9) & 15, mt = i >> 13;
    int r = lane & 15, kg = lane >> 4;
    int k = ks * 32 + kg * 8 + j;
    W1F[i] = f2bf(WU_d[(mt * 16 + r) * 768 + k]);
  } else if (i < 131072 + 262144) {
    int i2 = i - 131072;
    int j = i2 & 7, lane = (i2 >> 3) & 63, ks = (i2 >> 9) & 7, jt = i2 >> 12;
    int r = lane & 15, kg = lane >> 4;
    int k = ks * 32 + kg * 8 + j;
    W2F[i2] = f2bf(W_hh[(jt * 16 + r) * 256 + k]);
  } else if (i < 131072 + 262144 + 65536) {
    int i3 = i - (131072 + 262144);
    int j = i3 & 7, lane = (i3 >> 3) & 63, ks = (i3 >> 9) & 7, mt = i3 >> 12;
    int r = lane & 15, kg = lane >> 4;
    int k = 512 + ks * 32 + kg * 8 + j;
    WxF[i3] = f2bf(WU_d[(mt * 16 + r) * 768 + k]);
  } else if (i < 131072 + 262144 + 65536 + 1024) {
    int i4 = i - (131072 + 262144 + 65536);
    bsum[i4] = b_ih[i4] + b_hh[i4];
  }
}

// ---------------- prep: XW = X @ WU_dx^T (bf16) and XWl[b][t] = Wl[1:].X[b][t] ----------------
__global__ __launch_bounds__(256, 1) void prep_xw(
    const float* __restrict__ X,            // (T=128, B=1024, M=256) fp32
    const unsigned short* __restrict__ WxF,
    const float* __restrict__ Wl,           // 257
    unsigned short* __restrict__ XW,        // (B,T,M) bf16
    float* __restrict__ XWl) {              // (B,T) fp32
  __shared__ __align__(16) unsigned short XL[128 * 256];
  const int b = blockIdx.x, tid = threadIdx.x;
  for (int i = tid; i < 128 * 256; i += 256) {
    int t = i >> 8, k = i & 255;
    XL[i] = f2bf(X[(size_t)t * 262144 + (size_t)b * 256 + k]);
  }
  __syncthreads();
  const int wave = tid >> 6, lane = tid & 63, r = lane & 15, kg = lane >> 4;
  for (int tt = 0; tt < 8; ++tt) {
    uint4 a[8];
#pragma unroll
    for (int ks = 0; ks < 8; ++ks)
      a[ks] = *(const uint4*)&XL[(tt * 16 + r) * 256 + ks * 32 + kg * 8];
#pragma unroll
    for (int mtl = 0; mtl < 4; ++mtl) {
      const int mt = wave * 4 + mtl;
      f32x4 acc = {0.f, 0.f, 0.f, 0.f};
#pragma unroll
      for (int ks = 0; ks < 8; ++ks) {
        uint4 braw = *(const uint4*)(WxF + ((size_t)(mt * 8 + ks) * 64 + lane) * 8);
        acc = __builtin_amdgcn_mfma_f32_16x16x32_bf16(as_s8(a[ks]), as_s8(braw), acc, 0, 0, 0);
      }
#pragma unroll
      for (int rr = 0; rr < 4; ++rr) {
        int trow = tt * 16 + kg * 4 + rr;
        XW[(size_t)b * 32768 + trow * 256 + mt * 16 + r] = f2bf(acc[rr]);
      }
    }
  }
  // XWl: wave handles t in [wave*32, wave*32+32)
  float wl4[4];
#pragma unroll
  for (int j = 0; j < 4; ++j) wl4[j] = Wl[1 + lane * 4 + j];
  for (int t = wave * 32; t < wave * 32 + 32; ++t) {
    uint2 q = *(const uint2*)&XL[t * 256 + lane * 4];
    float s = wl4[0] * bf2f_lo(q.x) + wl4[1] * bf2f_hi(q.x) +
              wl4[2] * bf2f_lo(q.y) + wl4[3] * bf2f_hi(q.y);
#pragma unroll
    for (int off = 1; off < 64; off <<= 1) s += __shfl_xor(s, off, 64);
    if (lane == 0) XWl[b * 128 + t] = s;
  }
}

// ---------------- main scan: 1 block = 1024 thr = 16 waves = 4 batches x 4 waves ----------------
__global__ __launch_bounds__(1024, 4) void scan_k(
    const float* __restrict__ Yg,            // (1024,127,1)
    const float* __restrict__ X,             // (T,B,M) fp32 (final ctx only)
    const unsigned short* __restrict__ XW,   // (B,T,M) bf16
    const float* __restrict__ XWl,           // (B,T) fp32
    const unsigned short* __restrict__ W1F,
    const unsigned short* __restrict__ W2F,
    const float* __restrict__ bsum,          // 1024
    const float* __restrict__ v_d,           // 256
    const float* __restrict__ Wl,            // 257
    const float* __restrict__ W_ih,          // 1024
    const float* __restrict__ Wb_w,          // 256x512
    const float* __restrict__ Wb_b,          // 256
    const float* __restrict__ vb_w,          // 256
    const float* __restrict__ vb_b,          // 1
    float* __restrict__ outp) {              // 1024
  __shared__ __align__(16) unsigned short hcbf[16][520];  // [b][0:256)=h bf16, [256:512)=c bf16
  __shared__ __align__(16) float dWL[4][256];
  __shared__ float gL[4][1024];
  __shared__ float lL[4][128];
  __shared__ float betaL[4][128];
  __shared__ float ctxW[4][4][256];
  __shared__ float ctxL[4][256];
  __shared__ float ytL[4];

  const int tid = threadIdx.x;
  const int wave = tid >> 6;
  const int lane = tid & 63;
  const int r = lane & 15;
  const int kg = lane >> 4;
  const int b0 = blockIdx.x * 4;
  const int bb = wave >> 2;        // batch of this wave (0..3)
  const int tw = wave & 3;         // t-chunk of this wave (0..3)
  const int lp = tid & 255;        // LSTM p-index
  const int lb = tid >> 8;         // LSTM batch
  const int m8 = (lane & 31) * 8;  // score-pass m offset (8 bf16)
  const int th = lane >> 5;        // score-pass t parity

  const unsigned short* XWb = XW + (size_t)(b0 + bb) * (T_SZ * M_SZ);
  const float* Yb = Yg + (size_t)(b0 + wave) * NSTEP;  // only waves 0..3 use

  // ---- hoist: step-invariant XW score tile into registers (128 bf16/lane) ----
  uint4 xw[16];
  {
    const unsigned short* p = XWb + (tw * 32 + th) * M_SZ + m8;
#pragma unroll
    for (int i = 0; i < 16; ++i) xw[i] = *(const uint4*)(p + i * 512);
  }
  // step-invariant XWl pair (softmax waves only)
  float xwl0 = 0.f, xwl1 = 0.f;
  if (wave < 4) {
    const float* XWlb = XWl + (size_t)(b0 + wave) * T_SZ;
    xwl0 = XWlb[lane];
    xwl1 = XWlb[64 + lane];
  }

  for (int i = tid; i < 16 * 520; i += 1024) (&hcbf[0][0])[i] = 0;

  // per-lane preloads
  float v8[8];
#pragma unroll
  for (int j = 0; j < 8; ++j) v8[j] = v_d[m8 + j];
  float wih4g[4], bs4g[4];
#pragma unroll
  for (int g = 0; g < 4; ++g) { wih4g[g] = W_ih[g * 256 + lp]; bs4g[g] = bsum[g * 256 + lp]; }
  const float wl0 = Wl[0];
  float c_reg = 0.f;  // cell state for (lb, lp)

  __syncthreads();

  for (int step = 0; step < NSTEP; ++step) {
    // ---- G1: dW = d @ WU_dd^T; wave = mt tile (16 waves x 16 m each) ----
    {
      const int mt = wave;
      f32x4 acc = {0.f, 0.f, 0.f, 0.f};
      const unsigned short* bp = W1F + ((size_t)(mt * 16) * 64 + lane) * 8;
#pragma unroll
      for (int ks = 0; ks < 16; ++ks) {
        uint4 a = *(const uint4*)&hcbf[r][ks * 32 + kg * 8];
        uint4 braw = *(const uint4*)(bp + (size_t)ks * 512);
        acc = __builtin_amdgcn_mfma_f32_16x16x32_bf16(as_s8(a), as_s8(braw), acc, 0, 0, 0);
      }
      if (kg == 0) {
#pragma unroll
        for (int rr = 0; rr < 4; ++rr) dWL[rr][mt * 16 + r] = acc[rr];
      }
    }
    __syncthreads();

    // ---- scores: wave (bb,tw) covers t in [tw*32, tw*32+32), lane covers 8 m ----
    // XW tile lives in registers; pure VALU + one LDS broadcast read.
    {
      float dw8[8];
      *(f32x4*)&dw8[0] = *(const f32x4*)&dWL[bb][m8];
      *(f32x4*)&dw8[4] = *(const f32x4*)&dWL[bb][m8 + 4];
#pragma unroll
      for (int i = 0; i < 16; ++i) {
        uint4 q = xw[i];
        float s = v8[0] * tanh_f(dw8[0] + bf2f_lo(q.x)) + v8[1] * tanh_f(dw8[1] + bf2f_hi(q.x)) +
                  v8[2] * tanh_f(dw8[2] + bf2f_lo(q.y)) + v8[3] * tanh_f(dw8[3] + bf2f_hi(q.y)) +
                  v8[4] * tanh_f(dw8[4] + bf2f_lo(q.z)) + v8[5] * tanh_f(dw8[5] + bf2f_hi(q.z)) +
                  v8[6] * tanh_f(dw8[6] + bf2f_lo(q.w)) + v8[7] * tanh_f(dw8[7] + bf2f_hi(q.w));
#pragma unroll
        for (int off = 1; off < 32; off <<= 1) s += __shfl_xor(s, off, 64);
        if ((lane & 31) == 0) lL[bb][tw * 32 + 2 * i + th] = s;
      }
    }
    __syncthreads();

    // ---- softmax + y_tilde (waves 0..3, batch = wave) ----
    if (wave < 4) {
      float l0 = lL[wave][lane], l1 = lL[wave][64 + lane];
      float mx = fmaxf(l0, l1);
#pragma unroll
      for (int off = 1; off < 64; off <<= 1) mx = fmaxf(mx, __shfl_xor(mx, off, 64));
      float e0 = fexp2((l0 - mx) * 1.4426950408889634f);
      float e1 = fexp2((l1 - mx) * 1.4426950408889634f);
      float sm = e0 + e1;
      float yt = e0 * xwl0 + e1 * xwl1;
#pragma unroll
      for (int off = 1; off < 64; off <<= 1) {
        sm += __shfl_xor(sm, off, 64);
        yt += __shfl_xor(yt, off, 64);
      }
      float inv = frcp(sm);
      if (step == NSTEP - 1) {  // beta only needed for final ctx
        betaL[wave][lane] = e0 * inv;
        betaL[wave][64 + lane] = e1 * inv;
      }
      if (lane == 0) ytL[wave] = yt * inv + wl0 * Yb[step];
    }

    // ---- G2: gates = h @ W_hh^T; wave handles 4 jt tiles ----
    {
#pragma unroll
      for (int jtl = 0; jtl < 4; ++jtl) {
        const int jt = wave * 4 + jtl;
        f32x4 acc = {0.f, 0.f, 0.f, 0.f};
        const unsigned short* bp = W2F + ((size_t)(jt * 8) * 64 + lane) * 8;
#pragma unroll
        for (int ks = 0; ks < 8; ++ks) {
          uint4 a = *(const uint4*)&hcbf[r][ks * 32 + kg * 8];
          uint4 braw = *(const uint4*)(bp + (size_t)ks * 512);
          acc = __builtin_amdgcn_mfma_f32_16x16x32_bf16(as_s8(a), as_s8(braw), acc, 0, 0, 0);
        }
        if (kg == 0) {
#pragma unroll
          for (int rr = 0; rr < 4; ++rr) gL[rr][jt * 16 + r] = acc[rr];
        }
      }
    }
    __syncthreads();

    // ---- final-step ctx partials (needs betaL) ----
    if (step == NSTEP - 1) {
      const int m4 = lane * 4;
      f32x4 c4 = {0.f, 0.f, 0.f, 0.f};
      for (int t = tw * 32; t < tw * 32 + 32; ++t) {
        float bta = betaL[bb][t];
        f32x4 x4 = *(const f32x4*)&X[(size_t)t * 262144 + (size_t)(b0 + bb) * 256 + m4];
        c4.x += bta * x4.x;
        c4.y += bta * x4.y;
        c4.z += bta * x4.z;
        c4.w += bta * x4.w;
      }
      *(f32x4*)&ctxW[bb][tw][m4] = c4;
    }

    // ---- LSTM update: thread = (lb, lp) ----
    {
      float yt = ytL[lb];
      float ig = gL[lb][lp] + yt * wih4g[0] + bs4g[0];
      float fg = gL[lb][256 + lp] + yt * wih4g[1] + bs4g[1];
      float gg = gL[lb][512 + lp] + yt * wih4g[2] + bs4g[2];
      float og = gL[lb][768 + lp] + yt * wih4g[3] + bs4g[3];
      float cn = sigm_f(fg) * c_reg + sigm_f(ig) * tanh_f(gg);
      float hn = sigm_f(og) * tanh_f(cn);
      c_reg = cn;
      hcbf[lb][lp] = f2bf(hn);
      hcbf[lb][256 + lp] = f2bf(cn);
    }
    __syncthreads();
  }

  // ---- reduce ctx partials ----
  ctxL[lb][lp] = ctxW[lb][0][lp] + ctxW[lb][1][lp] + ctxW[lb][2][lp] + ctxW[lb][3][lp];
  __syncthreads();

  // ---- output head: waves 0..3, batch = wave ----
  if (wave < 4) {
    const int m4 = lane * 4;
    float h0 = 0.f, h1 = 0.f, h2 = 0.f, h3 = 0.f;
    for (int q = 0; q < 512; ++q) {
      float hcq = (q < 256) ? bf2f_lo((unsigned)hcbf[wave][q]) : ctxL[wave][q - 256];
      const float* wb = Wb_w + (size_t)m4 * 512 + q;
      h0 += hcq * wb[0];
      h1 += hcq * wb[512];
      h2 += hcq * wb[1024];
      h3 += hcq * wb[1536];
    }
    float o = (h0 + Wb_b[m4]) * vb_w[m4] + (h1 + Wb_b[m4 + 1]) * vb_w[m4 + 1] +
              (h2 + Wb_b[m4 + 2]) * vb_w[m4 + 2] + (h3 + Wb_b[m4 + 3]) * vb_w[m4 + 3];
#pragma unroll
    for (int off = 1; off < 64; off <<= 1) o += __shfl_xor(o, off, 64);
    if (lane == 0) outp[b0 + wave] = o + vb_b[0];
  }
}

extern "C" void kernel_launch(void* const* d_in, const int* in_sizes, int n_in,
                              void* d_out, int out_size, void* d_ws, size_t ws_size,
                              hipStream_t stream) {
  const float* Y = (const float*)d_in[0];
  const float* X = (const float*)d_in[1];
  const float* WU_d = (const float*)d_in[2];
  const float* v_d = (const float*)d_in[3];
  const float* Wl = (const float*)d_in[4];
  const float* W_ih = (const float*)d_in[5];
  const float* W_hh = (const float*)d_in[6];
  const float* b_ih = (const float*)d_in[7];
  const float* b_hh = (const float*)d_in[8];
  const float* Wb_w = (const float*)d_in[9];
  const float* Wb_b = (const float*)d_in[10];
  const float* vb_w = (const float*)d_in[11];
  const float* vb_b = (const float*)d_in[12];

  char* ws = (char*)d_ws;
  unsigned short* XW = (unsigned short*)(ws + 0);            // 64 MB
  float* XWl = (float*)(ws + 67108864);                      // 512 KB
  unsigned short* W1F = (unsigned short*)(ws + 67633152);    // 256 KB
  unsigned short* W2F = (unsigned short*)(ws + 67895296);    // 512 KB
  unsigned short* WxF = (unsigned short*)(ws + 68419584);    // 128 KB
  float* bsum = (float*)(ws + 68550656);                     // 4 KB

  prep_w<<<1796, 256, 0, stream>>>(WU_d, W_hh, b_ih, b_hh, W1F, W2F, WxF, bsum);
  prep_xw<<<1024, 256, 0, stream>>>(X, WxF, Wl, XW, XWl);
  scan_k<<<256, 1024, 0, stream>>>(Y, X, XW, XWl, W1F, W2F, bsum, v_d, Wl, W_ih,
                                   Wb_w, Wb_b, vb_w, vb_b, (float*)d_out);
}

// Round 2
// 6036.244 us; speedup vs baseline: 1.8001x; 1.8001x over previous
//
#include <hip/hip_runtime.h>

// Decoder scan: B=1024, T=128, M=256, P=256, 127 steps.
// R4: XW score tile (128 bf16/lane) pinned in 64 AGPRs via inline-asm "a"
// constraints (v_accvgpr_write/read). R3's plain-array hoist spilled to
// scratch (VGPR_Count stayed 64; +4GB fetch, +130MB write). AGPR half of the
// gfx950 unified RF holds the tile; VALU working set stays at 64 VGPRs ->
// total 128 = exact 4-waves/SIMD budget for 1024-thread blocks.

#define B_SZ 1024
#define T_SZ 128
#define M_SZ 256
#define NSTEP 127

typedef __attribute__((ext_vector_type(8))) short short8;
typedef __attribute__((ext_vector_type(4))) float f32x4;

__device__ __forceinline__ float bf2f_lo(unsigned u) {
  return __builtin_bit_cast(float, u << 16);
}
__device__ __forceinline__ float bf2f_hi(unsigned u) {
  return __builtin_bit_cast(float, u & 0xffff0000u);
}
__device__ __forceinline__ unsigned short f2bf(float f) {
  unsigned u = __builtin_bit_cast(unsigned, f);
  u = (u + 0x7fffu + ((u >> 16) & 1u)) >> 16;  // RNE
  return (unsigned short)u;
}
__device__ __forceinline__ float fexp2(float x) { return __builtin_amdgcn_exp2f(x); }
__device__ __forceinline__ float frcp(float x) { return __builtin_amdgcn_rcpf(x); }
__device__ __forceinline__ float tanh_f(float x) {
  float t = fexp2(x * 2.8853900817779268f);
  return 1.f - 2.f * frcp(t + 1.f);
}
__device__ __forceinline__ float sigm_f(float x) {
  return frcp(1.f + fexp2(x * -1.4426950408889634f));
}
__device__ __forceinline__ short8 as_s8(uint4 u) { return __builtin_bit_cast(short8, u); }

// ---------------- prep: weight bf16 fragment swizzles + bias sum ----------------
__global__ void prep_w(const float* __restrict__ WU_d,
                       const float* __restrict__ W_hh,
                       const float* __restrict__ b_ih,
                       const float* __restrict__ b_hh,
                       unsigned short* __restrict__ W1F,
                       unsigned short* __restrict__ W2F,
                       unsigned short* __restrict__ WxF,
                       float* __restrict__ bsum) {
  int i = blockIdx.x * 256 + threadIdx.x;
  if (i < 131072) {
    int j = i & 7, lane = (i >> 3) & 63, ks = (i >> 9) & 15, mt = i >> 13;
    int r = lane & 15, kg = lane >> 4;
    int k = ks * 32 + kg * 8 + j;
    W1F[i] = f2bf(WU_d[(mt * 16 + r) * 768 + k]);
  } else if (i < 131072 + 262144) {
    int i2 = i - 131072;
    int j = i2 & 7, lane = (i2 >> 3) & 63, ks = (i2 >> 9) & 7, jt = i2 >> 12;
    int r = lane & 15, kg = lane >> 4;
    int k = ks * 32 + kg * 8 + j;
    W2F[i2] = f2bf(W_hh[(jt * 16 + r) * 256 + k]);
  } else if (i < 131072 + 262144 + 65536) {
    int i3 = i - (131072 + 262144);
    int j = i3 & 7, lane = (i3 >> 3) & 63, ks = (i3 >> 9) & 7, mt = i3 >> 12;
    int r = lane & 15, kg = lane >> 4;
    int k = 512 + ks * 32 + kg * 8 + j;
    WxF[i3] = f2bf(WU_d[(mt * 16 + r) * 768 + k]);
  } else if (i < 131072 + 262144 + 65536 + 1024) {
    int i4 = i - (131072 + 262144 + 65536);
    bsum[i4] = b_ih[i4] + b_hh[i4];
  }
}

// ---------------- prep: XW = X @ WU_dx^T (bf16) and XWl[b][t] = Wl[1:].X[b][t] ----------------
__global__ __launch_bounds__(256, 1) void prep_xw(
    const float* __restrict__ X,            // (T=128, B=1024, M=256) fp32
    const unsigned short* __restrict__ WxF,
    const float* __restrict__ Wl,           // 257
    unsigned short* __restrict__ XW,        // (B,T,M) bf16
    float* __restrict__ XWl) {              // (B,T) fp32
  __shared__ __align__(16) unsigned short XL[128 * 256];
  const int b = blockIdx.x, tid = threadIdx.x;
  for (int i = tid; i < 128 * 256; i += 256) {
    int t = i >> 8, k = i & 255;
    XL[i] = f2bf(X[(size_t)t * 262144 + (size_t)b * 256 + k]);
  }
  __syncthreads();
  const int wave = tid >> 6, lane = tid & 63, r = lane & 15, kg = lane >> 4;
  for (int tt = 0; tt < 8; ++tt) {
    uint4 a[8];
#pragma unroll
    for (int ks = 0; ks < 8; ++ks)
      a[ks] = *(const uint4*)&XL[(tt * 16 + r) * 256 + ks * 32 + kg * 8];
#pragma unroll
    for (int mtl = 0; mtl < 4; ++mtl) {
      const int mt = wave * 4 + mtl;
      f32x4 acc = {0.f, 0.f, 0.f, 0.f};
#pragma unroll
      for (int ks = 0; ks < 8; ++ks) {
        uint4 braw = *(const uint4*)(WxF + ((size_t)(mt * 8 + ks) * 64 + lane) * 8);
        acc = __builtin_amdgcn_mfma_f32_16x16x32_bf16(as_s8(a[ks]), as_s8(braw), acc, 0, 0, 0);
      }
#pragma unroll
      for (int rr = 0; rr < 4; ++rr) {
        int trow = tt * 16 + kg * 4 + rr;
        XW[(size_t)b * 32768 + trow * 256 + mt * 16 + r] = f2bf(acc[rr]);
      }
    }
  }
  // XWl: wave handles t in [wave*32, wave*32+32)
  float wl4[4];
#pragma unroll
  for (int j = 0; j < 4; ++j) wl4[j] = Wl[1 + lane * 4 + j];
  for (int t = wave * 32; t < wave * 32 + 32; ++t) {
    uint2 q = *(const uint2*)&XL[t * 256 + lane * 4];
    float s = wl4[0] * bf2f_lo(q.x) + wl4[1] * bf2f_hi(q.x) +
              wl4[2] * bf2f_lo(q.y) + wl4[3] * bf2f_hi(q.y);
#pragma unroll
    for (int off = 1; off < 64; off <<= 1) s += __shfl_xor(s, off, 64);
    if (lane == 0) XWl[b * 128 + t] = s;
  }
}

// AGPR pin helpers: keep the step-invariant XW tile in the AGPR half of the
// unified register file so the VALU working set stays within 64 VGPRs.
#define XW_DECL(n) unsigned xa##n##_0, xa##n##_1, xa##n##_2, xa##n##_3;

#define XW_LOAD(n)                                                        \
  {                                                                       \
    uint4 t_ = *(const uint4*)(p_ + (n) * 512);                           \
    asm("v_accvgpr_write_b32 %0, %1" : "=a"(xa##n##_0) : "v"(t_.x));      \
    asm("v_accvgpr_write_b32 %0, %1" : "=a"(xa##n##_1) : "v"(t_.y));      \
    asm("v_accvgpr_write_b32 %0, %1" : "=a"(xa##n##_2) : "v"(t_.z));      \
    asm("v_accvgpr_write_b32 %0, %1" : "=a"(xa##n##_3) : "v"(t_.w));      \
  }

#define XW_SCORE(n)                                                          \
  {                                                                          \
    unsigned qx, qy, qz, qw;                                                 \
    asm("v_accvgpr_read_b32 %0, %1" : "=v"(qx) : "a"(xa##n##_0));            \
    asm("v_accvgpr_read_b32 %0, %1" : "=v"(qy) : "a"(xa##n##_1));            \
    asm("v_accvgpr_read_b32 %0, %1" : "=v"(qz) : "a"(xa##n##_2));            \
    asm("v_accvgpr_read_b32 %0, %1" : "=v"(qw) : "a"(xa##n##_3));            \
    float s = v8[0] * tanh_f(dw8[0] + bf2f_lo(qx)) +                         \
              v8[1] * tanh_f(dw8[1] + bf2f_hi(qx)) +                         \
              v8[2] * tanh_f(dw8[2] + bf2f_lo(qy)) +                         \
              v8[3] * tanh_f(dw8[3] + bf2f_hi(qy)) +                         \
              v8[4] * tanh_f(dw8[4] + bf2f_lo(qz)) +                         \
              v8[5] * tanh_f(dw8[5] + bf2f_hi(qz)) +                         \
              v8[6] * tanh_f(dw8[6] + bf2f_lo(qw)) +                         \
              v8[7] * tanh_f(dw8[7] + bf2f_hi(qw));                          \
    s += __shfl_xor(s, 1, 64);                                               \
    s += __shfl_xor(s, 2, 64);                                               \
    s += __shfl_xor(s, 4, 64);                                               \
    s += __shfl_xor(s, 8, 64);                                               \
    s += __shfl_xor(s, 16, 64);                                              \
    if ((lane & 31) == 0) lL[bb][tw * 32 + 2 * (n) + th] = s;                \
  }

// ---------------- main scan: 1 block = 1024 thr = 16 waves = 4 batches x 4 waves ----------------
__global__ __launch_bounds__(1024, 4) void scan_k(
    const float* __restrict__ Yg,            // (1024,127,1)
    const float* __restrict__ X,             // (T,B,M) fp32 (final ctx only)
    const unsigned short* __restrict__ XW,   // (B,T,M) bf16
    const float* __restrict__ XWl,           // (B,T) fp32
    const unsigned short* __restrict__ W1F,
    const unsigned short* __restrict__ W2F,
    const float* __restrict__ bsum,          // 1024
    const float* __restrict__ v_d,           // 256
    const float* __restrict__ Wl,            // 257
    const float* __restrict__ W_ih,          // 1024
    const float* __restrict__ Wb_w,          // 256x512
    const float* __restrict__ Wb_b,          // 256
    const float* __restrict__ vb_w,          // 256
    const float* __restrict__ vb_b,          // 1
    float* __restrict__ outp) {              // 1024
  __shared__ __align__(16) unsigned short hcbf[16][520];  // [b][0:256)=h bf16, [256:512)=c bf16
  __shared__ __align__(16) float dWL[4][256];
  __shared__ float gL[4][1024];
  __shared__ float lL[4][128];
  __shared__ float betaL[4][128];
  __shared__ float ctxW[4][4][256];
  __shared__ float ctxL[4][256];
  __shared__ float ytL[4];

  const int tid = threadIdx.x;
  const int wave = tid >> 6;
  const int lane = tid & 63;
  const int r = lane & 15;
  const int kg = lane >> 4;
  const int b0 = blockIdx.x * 4;
  const int bb = wave >> 2;        // batch of this wave (0..3)
  const int tw = wave & 3;         // t-chunk of this wave (0..3)
  const int lp = tid & 255;        // LSTM p-index
  const int lb = tid >> 8;         // LSTM batch
  const int m8 = (lane & 31) * 8;  // score-pass m offset (8 bf16)
  const int th = lane >> 5;        // score-pass t parity

  const unsigned short* XWb = XW + (size_t)(b0 + bb) * (T_SZ * M_SZ);
  const float* Yb = Yg + (size_t)(b0 + wave) * NSTEP;  // only waves 0..3 use

  // ---- hoist: step-invariant XW score tile into 64 AGPRs per lane ----
  XW_DECL(0) XW_DECL(1) XW_DECL(2) XW_DECL(3)
  XW_DECL(4) XW_DECL(5) XW_DECL(6) XW_DECL(7)
  XW_DECL(8) XW_DECL(9) XW_DECL(10) XW_DECL(11)
  XW_DECL(12) XW_DECL(13) XW_DECL(14) XW_DECL(15)
  {
    const unsigned short* p_ = XWb + (tw * 32 + th) * M_SZ + m8;
    XW_LOAD(0) XW_LOAD(1) XW_LOAD(2) XW_LOAD(3)
    XW_LOAD(4) XW_LOAD(5) XW_LOAD(6) XW_LOAD(7)
    XW_LOAD(8) XW_LOAD(9) XW_LOAD(10) XW_LOAD(11)
    XW_LOAD(12) XW_LOAD(13) XW_LOAD(14) XW_LOAD(15)
  }
  // step-invariant XWl pair (softmax waves only)
  float xwl0 = 0.f, xwl1 = 0.f;
  if (wave < 4) {
    const float* XWlb = XWl + (size_t)(b0 + wave) * T_SZ;
    xwl0 = XWlb[lane];
    xwl1 = XWlb[64 + lane];
  }

  for (int i = tid; i < 16 * 520; i += 1024) (&hcbf[0][0])[i] = 0;

  // per-lane preloads
  float v8[8];
#pragma unroll
  for (int j = 0; j < 8; ++j) v8[j] = v_d[m8 + j];
  float wih4g[4], bs4g[4];
#pragma unroll
  for (int g = 0; g < 4; ++g) { wih4g[g] = W_ih[g * 256 + lp]; bs4g[g] = bsum[g * 256 + lp]; }
  const float wl0 = Wl[0];
  float c_reg = 0.f;  // cell state for (lb, lp)

  __syncthreads();

  for (int step = 0; step < NSTEP; ++step) {
    // ---- G1: dW = d @ WU_dd^T; wave = mt tile (16 waves x 16 m each) ----
    {
      const int mt = wave;
      f32x4 acc = {0.f, 0.f, 0.f, 0.f};
      const unsigned short* bp = W1F + ((size_t)(mt * 16) * 64 + lane) * 8;
#pragma unroll
      for (int ks = 0; ks < 16; ++ks) {
        uint4 a = *(const uint4*)&hcbf[r][ks * 32 + kg * 8];
        uint4 braw = *(const uint4*)(bp + (size_t)ks * 512);
        acc = __builtin_amdgcn_mfma_f32_16x16x32_bf16(as_s8(a), as_s8(braw), acc, 0, 0, 0);
      }
      if (kg == 0) {
#pragma unroll
        for (int rr = 0; rr < 4; ++rr) dWL[rr][mt * 16 + r] = acc[rr];
      }
    }
    __syncthreads();

    // ---- scores: wave (bb,tw) covers t in [tw*32, tw*32+32), lane covers 8 m ----
    // XW tile lives in AGPRs; pure VALU + one LDS broadcast read.
    {
      float dw8[8];
      *(f32x4*)&dw8[0] = *(const f32x4*)&dWL[bb][m8];
      *(f32x4*)&dw8[4] = *(const f32x4*)&dWL[bb][m8 + 4];
      XW_SCORE(0) XW_SCORE(1) XW_SCORE(2) XW_SCORE(3)
      XW_SCORE(4) XW_SCORE(5) XW_SCORE(6) XW_SCORE(7)
      XW_SCORE(8) XW_SCORE(9) XW_SCORE(10) XW_SCORE(11)
      XW_SCORE(12) XW_SCORE(13) XW_SCORE(14) XW_SCORE(15)
    }
    __syncthreads();

    // ---- softmax + y_tilde (waves 0..3, batch = wave) ----
    if (wave < 4) {
      float l0 = lL[wave][lane], l1 = lL[wave][64 + lane];
      float mx = fmaxf(l0, l1);
#pragma unroll
      for (int off = 1; off < 64; off <<= 1) mx = fmaxf(mx, __shfl_xor(mx, off, 64));
      float e0 = fexp2((l0 - mx) * 1.4426950408889634f);
      float e1 = fexp2((l1 - mx) * 1.4426950408889634f);
      float sm = e0 + e1;
      float yt = e0 * xwl0 + e1 * xwl1;
#pragma unroll
      for (int off = 1; off < 64; off <<= 1) {
        sm += __shfl_xor(sm, off, 64);
        yt += __shfl_xor(yt, off, 64);
      }
      float inv = frcp(sm);
      if (step == NSTEP - 1) {  // beta only needed for final ctx
        betaL[wave][lane] = e0 * inv;
        betaL[wave][64 + lane] = e1 * inv;
      }
      if (lane == 0) ytL[wave] = yt * inv + wl0 * Yb[step];
    }

    // ---- G2: gates = h @ W_hh^T; wave handles 4 jt tiles ----
    {
#pragma unroll
      for (int jtl = 0; jtl < 4; ++jtl) {
        const int jt = wave * 4 + jtl;
        f32x4 acc = {0.f, 0.f, 0.f, 0.f};
        const unsigned short* bp = W2F + ((size_t)(jt * 8) * 64 + lane) * 8;
#pragma unroll
        for (int ks = 0; ks < 8; ++ks) {
          uint4 a = *(const uint4*)&hcbf[r][ks * 32 + kg * 8];
          uint4 braw = *(const uint4*)(bp + (size_t)ks * 512);
          acc = __builtin_amdgcn_mfma_f32_16x16x32_bf16(as_s8(a), as_s8(braw), acc, 0, 0, 0);
        }
        if (kg == 0) {
#pragma unroll
          for (int rr = 0; rr < 4; ++rr) gL[rr][jt * 16 + r] = acc[rr];
        }
      }
    }
    __syncthreads();

    // ---- final-step ctx partials (needs betaL) ----
    if (step == NSTEP - 1) {
      const int m4 = lane * 4;
      f32x4 c4 = {0.f, 0.f, 0.f, 0.f};
      for (int t = tw * 32; t < tw * 32 + 32; ++t) {
        float bta = betaL[bb][t];
        f32x4 x4 = *(const f32x4*)&X[(size_t)t * 262144 + (size_t)(b0 + bb) * 256 + m4];
        c4.x += bta * x4.x;
        c4.y += bta * x4.y;
        c4.z += bta * x4.z;
        c4.w += bta * x4.w;
      }
      *(f32x4*)&ctxW[bb][tw][m4] = c4;
    }

    // ---- LSTM update: thread = (lb, lp) ----
    {
      float yt = ytL[lb];
      float ig = gL[lb][lp] + yt * wih4g[0] + bs4g[0];
      float fg = gL[lb][256 + lp] + yt * wih4g[1] + bs4g[1];
      float gg = gL[lb][512 + lp] + yt * wih4g[2] + bs4g[2];
      float og = gL[lb][768 + lp] + yt * wih4g[3] + bs4g[3];
      float cn = sigm_f(fg) * c_reg + sigm_f(ig) * tanh_f(gg);
      float hn = sigm_f(og) * tanh_f(cn);
      c_reg = cn;
      hcbf[lb][lp] = f2bf(hn);
      hcbf[lb][256 + lp] = f2bf(cn);
    }
    __syncthreads();
  }

  // ---- reduce ctx partials ----
  ctxL[lb][lp] = ctxW[lb][0][lp] + ctxW[lb][1][lp] + ctxW[lb][2][lp] + ctxW[lb][3][lp];
  __syncthreads();

  // ---- output head: waves 0..3, batch = wave ----
  if (wave < 4) {
    const int m4 = lane * 4;
    float h0 = 0.f, h1 = 0.f, h2 = 0.f, h3 = 0.f;
    for (int q = 0; q < 512; ++q) {
      float hcq = (q < 256) ? bf2f_lo((unsigned)hcbf[wave][q]) : ctxL[wave][q - 256];
      const float* wb = Wb_w + (size_t)m4 * 512 + q;
      h0 += hcq * wb[0];
      h1 += hcq * wb[512];
      h2 += hcq * wb[1024];
      h3 += hcq * wb[1536];
    }
    float o = (h0 + Wb_b[m4]) * vb_w[m4] + (h1 + Wb_b[m4 + 1]) * vb_w[m4 + 1] +
              (h2 + Wb_b[m4 + 2]) * vb_w[m4 + 2] + (h3 + Wb_b[m4 + 3]) * vb_w[m4 + 3];
#pragma unroll
    for (int off = 1; off < 64; off <<= 1) o += __shfl_xor(o, off, 64);
    if (lane == 0) outp[b0 + wave] = o + vb_b[0];
  }
}

extern "C" void kernel_launch(void* const* d_in, const int* in_sizes, int n_in,
                              void* d_out, int out_size, void* d_ws, size_t ws_size,
                              hipStream_t stream) {
  const float* Y = (const float*)d_in[0];
  const float* X = (const float*)d_in[1];
  const float* WU_d = (const float*)d_in[2];
  const float* v_d = (const float*)d_in[3];
  const float* Wl = (const float*)d_in[4];
  const float* W_ih = (const float*)d_in[5];
  const float* W_hh = (const float*)d_in[6];
  const float* b_ih = (const float*)d_in[7];
  const float* b_hh = (const float*)d_in[8];
  const float* Wb_w = (const float*)d_in[9];
  const float* Wb_b = (const float*)d_in[10];
  const float* vb_w = (const float*)d_in[11];
  const float* vb_b = (const float*)d_in[12];

  char* ws = (char*)d_ws;
  unsigned short* XW = (unsigned short*)(ws + 0);            // 64 MB
  float* XWl = (float*)(ws + 67108864);                      // 512 KB
  unsigned short* W1F = (unsigned short*)(ws + 67633152);    // 256 KB
  unsigned short* W2F = (unsigned short*)(ws + 67895296);    // 512 KB
  unsigned short* WxF = (unsigned short*)(ws + 68419584);    // 128 KB
  float* bsum = (float*)(ws + 68550656);                     // 4 KB

  prep_w<<<1796, 256, 0, stream>>>(WU_d, W_hh, b_ih, b_hh, W1F, W2F, WxF, bsum);
  prep_xw<<<1024, 256, 0, stream>>>(X, WxF, Wl, XW, XWl);
  scan_k<<<256, 1024, 0, stream>>>(Y, X, XW, XWl, W1F, W2F, bsum, v_d, Wl, W_ih,
                                   Wb_w, Wb_b, vb_w, vb_b, (float*)d_out);
}

// Round 3
// 5327.266 us; speedup vs baseline: 2.0397x; 1.1331x over previous
//
#include <hip/hip_runtime.h>

// Decoder scan: B=1024, T=128, M=256, P=256, 127 steps.
// R5: weight loads were latency-serialized (R4 showed bytes don't matter:
// -44% fetch => -2% time). Replace per-iteration global weight loads in G1/G2
// with a per-wave global_load_lds DMA ring: 3 wave-private 2KB LDS panes,
// always 3 chunks (6 loads) in flight, counted vmcnt(4) waits, loads live
// across barriers (raw s_barrier + lgkmcnt, NOT __syncthreads which drains
// vmcnt). XW stays in 64 AGPRs (R4). Y preloaded to LDS so steady-state VMEM
// = ring only. hcbf shrunk to [4] rows (MFMA A rows 4-15 are broadcast
// copies; their C rows are discarded). ctx moved after the loop, union'd
// over the ring panes.

#define B_SZ 1024
#define T_SZ 128
#define M_SZ 256
#define NSTEP 127

typedef __attribute__((ext_vector_type(8))) short short8;
typedef __attribute__((ext_vector_type(4))) float f32x4;

__device__ __forceinline__ float bf2f_lo(unsigned u) {
  return __builtin_bit_cast(float, u << 16);
}
__device__ __forceinline__ float bf2f_hi(unsigned u) {
  return __builtin_bit_cast(float, u & 0xffff0000u);
}
__device__ __forceinline__ unsigned short f2bf(float f) {
  unsigned u = __builtin_bit_cast(unsigned, f);
  u = (u + 0x7fffu + ((u >> 16) & 1u)) >> 16;  // RNE
  return (unsigned short)u;
}
__device__ __forceinline__ float fexp2(float x) { return __builtin_amdgcn_exp2f(x); }
__device__ __forceinline__ float frcp(float x) { return __builtin_amdgcn_rcpf(x); }
__device__ __forceinline__ float tanh_f(float x) {
  float t = fexp2(x * 2.8853900817779268f);
  return 1.f - 2.f * frcp(t + 1.f);
}
__device__ __forceinline__ float sigm_f(float x) {
  return frcp(1.f + fexp2(x * -1.4426950408889634f));
}
__device__ __forceinline__ short8 as_s8(uint4 u) { return __builtin_bit_cast(short8, u); }

// ---------------- prep: weight bf16 fragment swizzles + bias sum ----------------
__global__ void prep_w(const float* __restrict__ WU_d,
                       const float* __restrict__ W_hh,
                       const float* __restrict__ b_ih,
                       const float* __restrict__ b_hh,
                       unsigned short* __restrict__ W1F,
                       unsigned short* __restrict__ W2F,
                       unsigned short* __restrict__ WxF,
                       float* __restrict__ bsum) {
  int i = blockIdx.x * 256 + threadIdx.x;
  if (i < 131072) {
    int j = i & 7, lane = (i >> 3) & 63, ks = (i >> 9) & 15, mt = i >> 13;
    int r = lane & 15, kg = lane >> 4;
    int k = ks * 32 + kg * 8 + j;
    W1F[i] = f2bf(WU_d[(mt * 16 + r) * 768 + k]);
  } else if (i < 131072 + 262144) {
    int i2 = i - 131072;
    int j = i2 & 7, lane = (i2 >> 3) & 63, ks = (i2 >> 9) & 7, jt = i2 >> 12;
    int r = lane & 15, kg = lane >> 4;
    int k = ks * 32 + kg * 8 + j;
    W2F[i2] = f2bf(W_hh[(jt * 16 + r) * 256 + k]);
  } else if (i < 131072 + 262144 + 65536) {
    int i3 = i - (131072 + 262144);
    int j = i3 & 7, lane = (i3 >> 3) & 63, ks = (i3 >> 9) & 7, mt = i3 >> 12;
    int r = lane & 15, kg = lane >> 4;
    int k = 512 + ks * 32 + kg * 8 + j;
    WxF[i3] = f2bf(WU_d[(mt * 16 + r) * 768 + k]);
  } else if (i < 131072 + 262144 + 65536 + 1024) {
    int i4 = i - (131072 + 262144 + 65536);
    bsum[i4] = b_ih[i4] + b_hh[i4];
  }
}

// ---------------- prep: XW = X @ WU_dx^T (bf16) and XWl[b][t] = Wl[1:].X[b][t] ----------------
__global__ __launch_bounds__(256, 1) void prep_xw(
    const float* __restrict__ X,            // (T=128, B=1024, M=256) fp32
    const unsigned short* __restrict__ WxF,
    const float* __restrict__ Wl,           // 257
    unsigned short* __restrict__ XW,        // (B,T,M) bf16
    float* __restrict__ XWl) {              // (B,T) fp32
  __shared__ __align__(16) unsigned short XL[128 * 256];
  const int b = blockIdx.x, tid = threadIdx.x;
  for (int i = tid; i < 128 * 256; i += 256) {
    int t = i >> 8, k = i & 255;
    XL[i] = f2bf(X[(size_t)t * 262144 + (size_t)b * 256 + k]);
  }
  __syncthreads();
  const int wave = tid >> 6, lane = tid & 63, r = lane & 15, kg = lane >> 4;
  for (int tt = 0; tt < 8; ++tt) {
    uint4 a[8];
#pragma unroll
    for (int ks = 0; ks < 8; ++ks)
      a[ks] = *(const uint4*)&XL[(tt * 16 + r) * 256 + ks * 32 + kg * 8];
#pragma unroll
    for (int mtl = 0; mtl < 4; ++mtl) {
      const int mt = wave * 4 + mtl;
      f32x4 acc = {0.f, 0.f, 0.f, 0.f};
#pragma unroll
      for (int ks = 0; ks < 8; ++ks) {
        uint4 braw = *(const uint4*)(WxF + ((size_t)(mt * 8 + ks) * 64 + lane) * 8);
        acc = __builtin_amdgcn_mfma_f32_16x16x32_bf16(as_s8(a[ks]), as_s8(braw), acc, 0, 0, 0);
      }
#pragma unroll
      for (int rr = 0; rr < 4; ++rr) {
        int trow = tt * 16 + kg * 4 + rr;
        XW[(size_t)b * 32768 + trow * 256 + mt * 16 + r] = f2bf(acc[rr]);
      }
    }
  }
  // XWl: wave handles t in [wave*32, wave*32+32)
  float wl4[4];
#pragma unroll
  for (int j = 0; j < 4; ++j) wl4[j] = Wl[1 + lane * 4 + j];
  for (int t = wave * 32; t < wave * 32 + 32; ++t) {
    uint2 q = *(const uint2*)&XL[t * 256 + lane * 4];
    float s = wl4[0] * bf2f_lo(q.x) + wl4[1] * bf2f_hi(q.x) +
              wl4[2] * bf2f_lo(q.y) + wl4[3] * bf2f_hi(q.y);
#pragma unroll
    for (int off = 1; off < 64; off <<= 1) s += __shfl_xor(s, off, 64);
    if (lane == 0) XWl[b * 128 + t] = s;
  }
}

// AGPR pin helpers: keep the step-invariant XW tile in the AGPR half of the
// unified register file so the VALU working set stays within 64 VGPRs.
#define XW_DECL(n) unsigned xa##n##_0, xa##n##_1, xa##n##_2, xa##n##_3;

#define XW_LOAD(n)                                                        \
  {                                                                       \
    uint4 t_ = *(const uint4*)(p_ + (n) * 512);                           \
    asm("v_accvgpr_write_b32 %0, %1" : "=a"(xa##n##_0) : "v"(t_.x));      \
    asm("v_accvgpr_write_b32 %0, %1" : "=a"(xa##n##_1) : "v"(t_.y));      \
    asm("v_accvgpr_write_b32 %0, %1" : "=a"(xa##n##_2) : "v"(t_.z));      \
    asm("v_accvgpr_write_b32 %0, %1" : "=a"(xa##n##_3) : "v"(t_.w));      \
  }

#define XW_SCORE(n)                                                          \
  {                                                                          \
    unsigned qx, qy, qz, qw;                                                 \
    asm("v_accvgpr_read_b32 %0, %1" : "=v"(qx) : "a"(xa##n##_0));            \
    asm("v_accvgpr_read_b32 %0, %1" : "=v"(qy) : "a"(xa##n##_1));            \
    asm("v_accvgpr_read_b32 %0, %1" : "=v"(qz) : "a"(xa##n##_2));            \
    asm("v_accvgpr_read_b32 %0, %1" : "=v"(qw) : "a"(xa##n##_3));            \
    float s = v8[0] * tanh_f(dw8[0] + bf2f_lo(qx)) +                         \
              v8[1] * tanh_f(dw8[1] + bf2f_hi(qx)) +                         \
              v8[2] * tanh_f(dw8[2] + bf2f_lo(qy)) +                         \
              v8[3] * tanh_f(dw8[3] + bf2f_hi(qy)) +                         \
              v8[4] * tanh_f(dw8[4] + bf2f_lo(qz)) +                         \
              v8[5] * tanh_f(dw8[5] + bf2f_hi(qz)) +                         \
              v8[6] * tanh_f(dw8[6] + bf2f_lo(qw)) +                         \
              v8[7] * tanh_f(dw8[7] + bf2f_hi(qw));                          \
    s += __shfl_xor(s, 1, 64);                                               \
    s += __shfl_xor(s, 2, 64);                                               \
    s += __shfl_xor(s, 4, 64);                                               \
    s += __shfl_xor(s, 8, 64);                                               \
    s += __shfl_xor(s, 16, 64);                                              \
    if ((lane & 31) == 0) lL[bb][tw * 32 + 2 * (n) + th] = s;                \
  }

// In-loop barrier: LDS producers drained, but vmcnt (DMA ring) stays in
// flight across the barrier (T4). __syncthreads would emit vmcnt(0).
#define BARL()                                               \
  do {                                                       \
    asm volatile("s_waitcnt lgkmcnt(0)" ::: "memory");       \
    __builtin_amdgcn_s_barrier();                            \
  } while (0)

// Ring waits: oldest in-flight chunk landed when <=4 loads outstanding.
#define RWAIT()                                              \
  do {                                                       \
    asm volatile("s_waitcnt vmcnt(4)" ::: "memory");         \
    __builtin_amdgcn_sched_barrier(0);                       \
  } while (0)

// ---------------- main scan: 1 block = 1024 thr = 16 waves = 4 batches x 4 waves ----------------
__global__ __launch_bounds__(1024, 4) void scan_k(
    const float* __restrict__ Yg,            // (1024,127,1)
    const float* __restrict__ X,             // (T,B,M) fp32 (final ctx only)
    const unsigned short* __restrict__ XW,   // (B,T,M) bf16
    const float* __restrict__ XWl,           // (B,T) fp32
    const unsigned short* __restrict__ W1F,
    const unsigned short* __restrict__ W2F,
    const float* __restrict__ bsum,          // 1024
    const float* __restrict__ v_d,           // 256
    const float* __restrict__ Wl,            // 257
    const float* __restrict__ W_ih,          // 1024
    const float* __restrict__ Wb_w,          // 256x512
    const float* __restrict__ Wb_b,          // 256
    const float* __restrict__ vb_w,          // 256
    const float* __restrict__ vb_b,          // 1
    float* __restrict__ outp) {              // 1024
  __shared__ __align__(16) unsigned short hcbf[4][520];  // [b][0:256)=h, [256:512)=c (bf16)
  __shared__ __align__(16) float dWL[4][256];
  __shared__ float gL[4][1024];
  __shared__ float lL[4][128];
  __shared__ float betaL[4][128];
  __shared__ float yL[4][128];
  __shared__ float ytL[4];
  // DMA ring: 16 waves x 3 panes x 1024 shorts (2 KB). Reused for ctx after
  // the loop (drained first): ctxW = first 16 KB, ctxL = next 4 KB.
  __shared__ __align__(16) unsigned short ringS[16 * 3 * 1024];

  const int tid = threadIdx.x;
  const int wave = tid >> 6;
  const int lane = tid & 63;
  const int r = lane & 15;
  const int kg = lane >> 4;
  const int b0 = blockIdx.x * 4;
  const int bb = wave >> 2;        // batch of this wave (0..3)
  const int tw = wave & 3;         // t-chunk of this wave (0..3)
  const int lp = tid & 255;        // LSTM p-index
  const int lb = tid >> 8;         // LSTM batch
  const int m8 = (lane & 31) * 8;  // score-pass m offset (8 bf16)
  const int th = lane >> 5;        // score-pass t parity

  const unsigned short* XWb = XW + (size_t)(b0 + bb) * (T_SZ * M_SZ);

  // ---- hoist: step-invariant XW score tile into 64 AGPRs per lane ----
  XW_DECL(0) XW_DECL(1) XW_DECL(2) XW_DECL(3)
  XW_DECL(4) XW_DECL(5) XW_DECL(6) XW_DECL(7)
  XW_DECL(8) XW_DECL(9) XW_DECL(10) XW_DECL(11)
  XW_DECL(12) XW_DECL(13) XW_DECL(14) XW_DECL(15)
  {
    const unsigned short* p_ = XWb + (tw * 32 + th) * M_SZ + m8;
    XW_LOAD(0) XW_LOAD(1) XW_LOAD(2) XW_LOAD(3)
    XW_LOAD(4) XW_LOAD(5) XW_LOAD(6) XW_LOAD(7)
    XW_LOAD(8) XW_LOAD(9) XW_LOAD(10) XW_LOAD(11)
    XW_LOAD(12) XW_LOAD(13) XW_LOAD(14) XW_LOAD(15)
  }
  // step-invariant XWl pair (softmax waves only)
  float xwl0 = 0.f, xwl1 = 0.f;
  if (wave < 4) {
    const float* XWlb = XWl + (size_t)(b0 + wave) * T_SZ;
    xwl0 = XWlb[lane];
    xwl1 = XWlb[64 + lane];
  }

  // init LDS: hcbf zeros, Y preload (removes per-step global loads so the
  // steady-state vmcnt stream is the weight ring ONLY)
  for (int i = tid; i < 4 * 520; i += 1024) (&hcbf[0][0])[i] = 0;
  for (int i = tid; i < 512; i += 1024) {
    int b = i >> 7, s = i & 127;
    yL[b][s] = (s < NSTEP) ? Yg[(size_t)(b0 + b) * NSTEP + s] : 0.f;
  }

  // per-lane preloads
  float v8[8];
#pragma unroll
  for (int j = 0; j < 8; ++j) v8[j] = v_d[m8 + j];
  float wih4g[4], bs4g[4];
#pragma unroll
  for (int g = 0; g < 4; ++g) { wih4g[g] = W_ih[g * 256 + lp]; bs4g[g] = bsum[g * 256 + lp]; }
  const float wl0 = Wl[0];
  float c_reg = 0.f;  // cell state for (lb, lp)

  // ---- DMA ring setup: per wave, 24 chunks/step of 2x1KB global_load_lds ----
  // chunk q<8: G1 (W1F, ks pair 2q,2q+1); q>=8: G2 jt=wave*4+((q-8)>>2),
  // ks pair 2*((q-8)&3). Weights are step-invariant so the ring cycles q
  // forever (phantom issues past the last step read valid memory).
  const unsigned short* const W1b = W1F + (size_t)wave * 8192 + (size_t)lane * 8;
  const unsigned short* const W2b = W2F + (size_t)wave * 4 * 4096 + (size_t)lane * 8;
  unsigned short* const ringW = &ringS[wave * 3 * 1024];
  int iq = 0, ip = 0;  // issue cursor: chunk-in-step, pane
  auto RISSUE = [&]() {
    const unsigned short* s = (iq < 8) ? (W1b + iq * 1024)
                                       : (W2b + ((iq - 8) >> 2) * 4096 + ((iq - 8) & 3) * 1024);
    unsigned short* d = ringW + ip * 1024;
    __builtin_amdgcn_global_load_lds((const unsigned int*)s, (unsigned int*)d, 16, 0, 0);
    __builtin_amdgcn_global_load_lds((const unsigned int*)(s + 512), (unsigned int*)(d + 512), 16, 0, 0);
    iq = (iq == 23) ? 0 : iq + 1;
    ip = (ip == 2) ? 0 : ip + 1;
  };
  int cp = 0;  // consume pane

  // prologue: 3 chunks in flight
  RISSUE();
  RISSUE();
  RISSUE();

  __syncthreads();  // one-time full barrier (drains prologue; counting stays valid)

  for (int step = 0; step < NSTEP; ++step) {
    // ---- G1: dW = d @ WU_dd^T; wave = mt tile; B-operand from DMA ring ----
    {
      f32x4 acc = {0.f, 0.f, 0.f, 0.f};
#pragma unroll
      for (int c = 0; c < 8; ++c) {
        RWAIT();
        const unsigned short* pb = ringW + cp * 1024 + lane * 8;
        uint4 bw0 = *(const uint4*)(pb);
        uint4 bw1 = *(const uint4*)(pb + 512);
        uint4 a0 = *(const uint4*)&hcbf[r & 3][(2 * c) * 32 + kg * 8];
        uint4 a1 = *(const uint4*)&hcbf[r & 3][(2 * c + 1) * 32 + kg * 8];
        acc = __builtin_amdgcn_mfma_f32_16x16x32_bf16(as_s8(a0), as_s8(bw0), acc, 0, 0, 0);
        acc = __builtin_amdgcn_mfma_f32_16x16x32_bf16(as_s8(a1), as_s8(bw1), acc, 0, 0, 0);
        asm volatile("s_waitcnt lgkmcnt(0)" ::: "memory");  // pane reads done
        __builtin_amdgcn_sched_barrier(0);
        RISSUE();  // refill this pane (chunk +3)
        cp = (cp == 2) ? 0 : cp + 1;
      }
      if (kg == 0) {
#pragma unroll
        for (int rr = 0; rr < 4; ++rr) dWL[rr][wave * 16 + r] = acc[rr];
      }
    }
    BARL();

    // ---- scores: wave (bb,tw) covers t in [tw*32, tw*32+32), lane covers 8 m ----
    {
      float dw8[8];
      *(f32x4*)&dw8[0] = *(const f32x4*)&dWL[bb][m8];
      *(f32x4*)&dw8[4] = *(const f32x4*)&dWL[bb][m8 + 4];
      XW_SCORE(0) XW_SCORE(1) XW_SCORE(2) XW_SCORE(3)
      XW_SCORE(4) XW_SCORE(5) XW_SCORE(6) XW_SCORE(7)
      XW_SCORE(8) XW_SCORE(9) XW_SCORE(10) XW_SCORE(11)
      XW_SCORE(12) XW_SCORE(13) XW_SCORE(14) XW_SCORE(15)
    }
    BARL();

    // ---- softmax + y_tilde (waves 0..3, batch = wave) ----
    if (wave < 4) {
      float l0 = lL[wave][lane], l1 = lL[wave][64 + lane];
      float mx = fmaxf(l0, l1);
#pragma unroll
      for (int off = 1; off < 64; off <<= 1) mx = fmaxf(mx, __shfl_xor(mx, off, 64));
      float e0 = fexp2((l0 - mx) * 1.4426950408889634f);
      float e1 = fexp2((l1 - mx) * 1.4426950408889634f);
      float sm = e0 + e1;
      float yt = e0 * xwl0 + e1 * xwl1;
#pragma unroll
      for (int off = 1; off < 64; off <<= 1) {
        sm += __shfl_xor(sm, off, 64);
        yt += __shfl_xor(yt, off, 64);
      }
      float inv = frcp(sm);
      if (step == NSTEP - 1) {  // beta only needed for final ctx
        betaL[wave][lane] = e0 * inv;
        betaL[wave][64 + lane] = e1 * inv;
      }
      if (lane == 0) ytL[wave] = yt * inv + wl0 * yL[wave][step];
    }

    // ---- G2: gates = h @ W_hh^T; wave handles 4 jt tiles; B from ring ----
    {
#pragma unroll
      for (int jtl = 0; jtl < 4; ++jtl) {
        f32x4 acc = {0.f, 0.f, 0.f, 0.f};
#pragma unroll
        for (int kp = 0; kp < 4; ++kp) {
          RWAIT();
          const unsigned short* pb = ringW + cp * 1024 + lane * 8;
          uint4 bw0 = *(const uint4*)(pb);
          uint4 bw1 = *(const uint4*)(pb + 512);
          uint4 a0 = *(const uint4*)&hcbf[r & 3][(2 * kp) * 32 + kg * 8];
          uint4 a1 = *(const uint4*)&hcbf[r & 3][(2 * kp + 1) * 32 + kg * 8];
          acc = __builtin_amdgcn_mfma_f32_16x16x32_bf16(as_s8(a0), as_s8(bw0), acc, 0, 0, 0);
          acc = __builtin_amdgcn_mfma_f32_16x16x32_bf16(as_s8(a1), as_s8(bw1), acc, 0, 0, 0);
          asm volatile("s_waitcnt lgkmcnt(0)" ::: "memory");
          __builtin_amdgcn_sched_barrier(0);
          RISSUE();
          cp = (cp == 2) ? 0 : cp + 1;
        }
        if (kg == 0) {
#pragma unroll
          for (int rr = 0; rr < 4; ++rr) gL[rr][(wave * 4 + jtl) * 16 + r] = acc[rr];
        }
      }
    }
    BARL();

    // ---- LSTM update: thread = (lb, lp) ----
    {
      float yt = ytL[lb];
      float ig = gL[lb][lp] + yt * wih4g[0] + bs4g[0];
      float fg = gL[lb][256 + lp] + yt * wih4g[1] + bs4g[1];
      float gg = gL[lb][512 + lp] + yt * wih4g[2] + bs4g[2];
      float og = gL[lb][768 + lp] + yt * wih4g[3] + bs4g[3];
      float cn = sigm_f(fg) * c_reg + sigm_f(ig) * tanh_f(gg);
      float hn = sigm_f(og) * tanh_f(cn);
      c_reg = cn;
      hcbf[lb][lp] = f2bf(hn);
      hcbf[lb][256 + lp] = f2bf(cn);
    }
    BARL();
  }

  // ---- drain the DMA ring, then reuse pane LDS for ctx ----
  asm volatile("s_waitcnt vmcnt(0)" ::: "memory");
  __syncthreads();
  float* ctxW = (float*)ringS;           // [4][4][256]
  float* ctxL = (float*)ringS + 4096;    // [4][256]

  // ---- ctx partials from final-step beta (wave (bb,tw) covers 32 t) ----
  {
    const int m4 = lane * 4;
    f32x4 c4 = {0.f, 0.f, 0.f, 0.f};
    for (int t = tw * 32; t < tw * 32 + 32; ++t) {
      float bta = betaL[bb][t];
      f32x4 x4 = *(const f32x4*)&X[(size_t)t * 262144 + (size_t)(b0 + bb) * 256 + m4];
      c4.x += bta * x4.x;
      c4.y += bta * x4.y;
      c4.z += bta * x4.z;
      c4.w += bta * x4.w;
    }
    *(f32x4*)&ctxW[(bb * 4 + tw) * 256 + m4] = c4;
  }
  __syncthreads();

  // ---- reduce ctx partials ----
  ctxL[lb * 256 + lp] = ctxW[(lb * 4 + 0) * 256 + lp] + ctxW[(lb * 4 + 1) * 256 + lp] +
                        ctxW[(lb * 4 + 2) * 256 + lp] + ctxW[(lb * 4 + 3) * 256 + lp];
  __syncthreads();

  // ---- output head: waves 0..3, batch = wave ----
  if (wave < 4) {
    const int m4 = lane * 4;
    float h0 = 0.f, h1 = 0.f, h2 = 0.f, h3 = 0.f;
    for (int q = 0; q < 512; ++q) {
      float hcq = (q < 256) ? bf2f_lo((unsigned)hcbf[wave][q]) : ctxL[wave * 256 + q - 256];
      const float* wb = Wb_w + (size_t)m4 * 512 + q;
      h0 += hcq * wb[0];
      h1 += hcq * wb[512];
      h2 += hcq * wb[1024];
      h3 += hcq * wb[1536];
    }
    float o = (h0 + Wb_b[m4]) * vb_w[m4] + (h1 + Wb_b[m4 + 1]) * vb_w[m4 + 1] +
              (h2 + Wb_b[m4 + 2]) * vb_w[m4 + 2] + (h3 + Wb_b[m4 + 3]) * vb_w[m4 + 3];
#pragma unroll
    for (int off = 1; off < 64; off <<= 1) o += __shfl_xor(o, off, 64);
    if (lane == 0) outp[b0 + wave] = o + vb_b[0];
  }
}

extern "C" void kernel_launch(void* const* d_in, const int* in_sizes, int n_in,
                              void* d_out, int out_size, void* d_ws, size_t ws_size,
                              hipStream_t stream) {
  const float* Y = (const float*)d_in[0];
  const float* X = (const float*)d_in[1];
  const float* WU_d = (const float*)d_in[2];
  const float* v_d = (const float*)d_in[3];
  const float* Wl = (const float*)d_in[4];
  const float* W_ih = (const float*)d_in[5];
  const float* W_hh = (const float*)d_in[6];
  const float* b_ih = (const float*)d_in[7];
  const float* b_hh = (const float*)d_in[8];
  const float* Wb_w = (const float*)d_in[9];
  const float* Wb_b = (const float*)d_in[10];
  const float* vb_w = (const float*)d_in[11];
  const float* vb_b = (const float*)d_in[12];

  char* ws = (char*)d_ws;
  unsigned short* XW = (unsigned short*)(ws + 0);            // 64 MB
  float* XWl = (float*)(ws + 67108864);                      // 512 KB
  unsigned short* W1F = (unsigned short*)(ws + 67633152);    // 256 KB
  unsigned short* W2F = (unsigned short*)(ws + 67895296);    // 512 KB
  unsigned short* WxF = (unsigned short*)(ws + 68419584);    // 128 KB
  float* bsum = (float*)(ws + 68550656);                     // 4 KB

  prep_w<<<1796, 256, 0, stream>>>(WU_d, W_hh, b_ih, b_hh, W1F, W2F, WxF, bsum);
  prep_xw<<<1024, 256, 0, stream>>>(X, WxF, Wl, XW, XWl);
  scan_k<<<256, 1024, 0, stream>>>(Y, X, XW, XWl, W1F, W2F, bsum, v_d, Wl, W_ih,
                                   Wb_w, Wb_b, vb_w, vb_b, (float*)d_out);
}